// Round 8
// baseline (299.460 us; speedup 1.0000x reference)
//
#include <hip/hip_runtime.h>
#include <hip/hip_bf16.h>
#include <cmath>

#define NB 4
#define NS 1024
#define ND 1024
#define NH 16
#define NDH 64
#define NKSP 32
#define SCALE 0.125f   // 1/sqrt(64)

typedef __attribute__((ext_vector_type(8))) short bf16x8;
typedef __attribute__((ext_vector_type(4))) float f32x4;
typedef unsigned long long u64;

#define AS1 __attribute__((address_space(1)))
#define AS3 __attribute__((address_space(3)))

__device__ __forceinline__ void gl_lds16(const void* g, void* l) {
    __builtin_amdgcn_global_load_lds((const AS1 void*)g, (AS3 void*)l, 16, 0, 0);
}

__device__ __forceinline__ ushort f2bf(float f) {
    union { __hip_bfloat16 h; ushort u; } cv;
    cv.h = __float2bfloat16(f);
    return cv.u;
}
__device__ __forceinline__ float bf2f(ushort u) {
    union { unsigned int i; float f; } cv;
    cv.i = ((unsigned int)u) << 16;
    return cv.f;
}

// ---------------------------------------------------------------------------
// y=0: x->bf16 (4096 blocks); y=1..4: W->bf16 (1024 blocks);
// y=5: pack pmask into bitwords (4096 blocks, one wave per u64 word).
// ---------------------------------------------------------------------------
__global__ __launch_bounds__(256)
void f2bf_multi(const float* __restrict__ x,
                const float* __restrict__ w0, const float* __restrict__ w1,
                const float* __restrict__ w2, const float* __restrict__ w3,
                const int* __restrict__ pm,
                ushort* __restrict__ xo,
                ushort* __restrict__ o0, ushort* __restrict__ o1,
                ushort* __restrict__ o2, ushort* __restrict__ o3,
                u64* __restrict__ bm)
{
    int y = blockIdx.y;
    if (y == 5) {
        int word = blockIdx.x * 4 + (threadIdx.x >> 6);
        int lane = threadIdx.x & 63;
        int row  = word >> 4, wcol = word & 15;
        int v = pm[(size_t)row * NS + wcol * 64 + lane];
        u64 b = __ballot(v != 0);
        if (lane == 0) bm[word] = b;
        return;
    }
    const float* src; ushort* dst; int nblk;
    if (y == 0)      { src = x;  dst = xo; nblk = 4096; }
    else if (y == 1) { src = w0; dst = o0; nblk = 1024; }
    else if (y == 2) { src = w1; dst = o1; nblk = 1024; }
    else if (y == 3) { src = w2; dst = o2; nblk = 1024; }
    else             { src = w3; dst = o3; nblk = 1024; }
    if (blockIdx.x >= (unsigned)nblk) return;
    int i = (blockIdx.x * 256 + threadIdx.x) * 4;
    float4 v = *(const float4*)&src[i];
    ushort4 o;
    o.x = f2bf(v.x); o.y = f2bf(v.y); o.z = f2bf(v.z); o.w = f2bf(v.w);
    *(ushort4*)&dst[i] = o;
}

// ---------------------------------------------------------------------------
// Fused QKV GEMM (R6 epilogue: direct scatter, V also writes Vt).
// grid (24,32): blockIdx.x: [0,8)=Q [8,16)=K [16,24)=V.
// ---------------------------------------------------------------------------
__global__ __launch_bounds__(256)
void gemm_qkv(const ushort* __restrict__ xb,
              const ushort* __restrict__ Wqb, const ushort* __restrict__ Wkb,
              const ushort* __restrict__ Wvb,
              const float* __restrict__ bq, const float* __restrict__ bk,
              const float* __restrict__ bv,
              ushort* __restrict__ Qo, ushort* __restrict__ Ko,
              ushort* __restrict__ Vo, ushort* __restrict__ Vto)
{
    constexpr int K = ND;
    __shared__ __attribute__((aligned(16))) ushort As[128 * 32];
    __shared__ __attribute__((aligned(16))) ushort Bs[128 * 32];

    const int tid  = threadIdx.x;
    const int lane = tid & 63, w = tid >> 6;
    const int wm = w >> 1, wn = w & 1;
    const int which = blockIdx.x >> 3;
    const int n0 = (blockIdx.x & 7) * 128;
    const int m0 = blockIdx.y * 128;
    const int quad = lane >> 4, l16 = lane & 15;

    const ushort* W = (which == 0) ? Wqb : (which == 1) ? Wkb : Wvb;
    const float* bias = (which == 0) ? bq : (which == 1) ? bk : bv;
    ushort* Out = (which == 0) ? Qo : (which == 1) ? Ko : Vo;

    f32x4 acc[4][4] = {};

    for (int k0 = 0; k0 < K; k0 += 32) {
        __syncthreads();
#pragma unroll
        for (int u = 0; u < 2; ++u) {
            int t0 = u * 256 + w * 64;
            int t  = t0 + lane;
            int row = t >> 2, kc = (t & 3) * 8;
            gl_lds16(xb + (size_t)(m0 + row) * K + k0 + kc, &As[t0 * 8]);
            gl_lds16(W  + (size_t)(n0 + row) * K + k0 + kc, &Bs[t0 * 8]);
        }
        __syncthreads();

        bf16x8 af[4], bfr[4];
#pragma unroll
        for (int mt = 0; mt < 4; ++mt)
            af[mt] = *(const bf16x8*)&As[(wm*64 + mt*16 + l16) * 32 + quad*8];
#pragma unroll
        for (int nt = 0; nt < 4; ++nt)
            bfr[nt] = *(const bf16x8*)&Bs[(wn*64 + nt*16 + l16) * 32 + quad*8];
#pragma unroll
        for (int mt = 0; mt < 4; ++mt)
#pragma unroll
            for (int nt = 0; nt < 4; ++nt)
                acc[mt][nt] = __builtin_amdgcn_mfma_f32_16x16x32_bf16(
                    af[mt], bfr[nt], acc[mt][nt], 0, 0, 0);
    }

#pragma unroll
    for (int nt = 0; nt < 4; ++nt) {
        int n = n0 + wn*64 + nt*16 + l16;
        float bz = bias[n];
        int hh = n >> 6, dh = n & 63;
#pragma unroll
        for (int mt = 0; mt < 4; ++mt) {
#pragma unroll
            for (int rg = 0; rg < 4; ++rg) {
                int m = m0 + wm*64 + mt*16 + quad*4 + rg;
                int b = m >> 10, s = m & (NS - 1);
                ushort val = f2bf(acc[mt][nt][rg] + bz);
                Out[(((size_t)(b*NH + hh))*NS + s)*NDH + dh] = val;
                if (which == 2)
                    Vto[(((size_t)(b*NH + hh))*NDH + dh)*NS + s] = val;
            }
        }
    }
}

// ---------------------------------------------------------------------------
// Output GEMM: 64x128 tile -> 512 blocks.
// ---------------------------------------------------------------------------
__global__ __launch_bounds__(256)
void gemm_out(const ushort* __restrict__ A, const ushort* __restrict__ W,
              const float* __restrict__ bias, float* __restrict__ Cout)
{
    constexpr int K = ND;
    __shared__ __attribute__((aligned(16))) ushort As[64 * 32];
    __shared__ __attribute__((aligned(16))) ushort Bs[128 * 32];

    const int tid  = threadIdx.x;
    const int lane = tid & 63, w = tid >> 6;
    const int wm = w & 1, wn = w >> 1;
    const int m0 = blockIdx.y * 64, n0 = blockIdx.x * 128;
    const int quad = lane >> 4, l16 = lane & 15;

    f32x4 acc[2][4] = {};

    for (int k0 = 0; k0 < K; k0 += 32) {
        __syncthreads();
        {
            int t0 = w * 64;
            int t  = t0 + lane;
            int row = t >> 2, kc = (t & 3) * 8;
            gl_lds16(A + (size_t)(m0 + row) * K + k0 + kc, &As[t0 * 8]);
        }
#pragma unroll
        for (int u = 0; u < 2; ++u) {
            int t0 = u * 256 + w * 64;
            int t  = t0 + lane;
            int row = t >> 2, kc = (t & 3) * 8;
            gl_lds16(W + (size_t)(n0 + row) * K + k0 + kc, &Bs[t0 * 8]);
        }
        __syncthreads();

        bf16x8 af[2], bfr[4];
#pragma unroll
        for (int mt = 0; mt < 2; ++mt)
            af[mt] = *(const bf16x8*)&As[(wm*32 + mt*16 + l16) * 32 + quad*8];
#pragma unroll
        for (int nt = 0; nt < 4; ++nt)
            bfr[nt] = *(const bf16x8*)&Bs[(wn*64 + nt*16 + l16) * 32 + quad*8];
#pragma unroll
        for (int mt = 0; mt < 2; ++mt)
#pragma unroll
            for (int nt = 0; nt < 4; ++nt)
                acc[mt][nt] = __builtin_amdgcn_mfma_f32_16x16x32_bf16(
                    af[mt], bfr[nt], acc[mt][nt], 0, 0, 0);
    }

#pragma unroll
    for (int nt = 0; nt < 4; ++nt) {
        int n = n0 + wn*64 + nt*16 + l16;
        float bz = bias[n];
#pragma unroll
        for (int mt = 0; mt < 2; ++mt) {
#pragma unroll
            for (int rg = 0; rg < 4; ++rg) {
                int m = m0 + wm*32 + mt*16 + quad*4 + rg;
                Cout[(size_t)m * ND + n] = acc[mt][nt][rg] + bz;
            }
        }
    }
}

// ---------------------------------------------------------------------------
// Split-K MFMA flash attention. Grid 1024: each block = 128 q-rows x 8
// K-tiles (split sp in {0,1}). Head->XCD map stride-8: XCD x owns heads
// {x, x+8, ..., x+56} (2 heads per batch per XCD -> dense work always
// spreads across all XCDs; K/Vt L2-local per XCD). No-max softmax makes
// split-K combine a pure sum: dense blocks atomicAdd unnormalized o into
// Od (fp32 scratch = d_out, memset to 0) and l into Lb; norm_attn divides.
// Sparse: sp=0 block only, scalar fp32, writes Awb directly.
// LDS = 9216*2 + 18432 + 8192 = 45056 B -> 3 blocks/CU.
// ---------------------------------------------------------------------------
__global__ __launch_bounds__(256)
void attn_split(const ushort* __restrict__ Qb, const ushort* __restrict__ Kb,
                const ushort* __restrict__ Vb, const ushort* __restrict__ Vt,
                const u64* __restrict__ bm,
                const int* __restrict__ pidx, const int* __restrict__ pimask,
                const float* __restrict__ u_prev,
                float* __restrict__ Od, float* __restrict__ Lb,
                ushort* __restrict__ OA)
{
    __shared__ __attribute__((aligned(16))) ushort Ks[64 * 72];
    __shared__ __attribute__((aligned(16))) ushort Vts[64 * 72];
    __shared__ __attribute__((aligned(16))) ushort Ps[128 * 72];
    __shared__ __attribute__((aligned(16))) u64    MW[128 * 8];

    const int tid  = threadIdx.x;
    const int lane = tid & 63, w = tid >> 6;
    const int quad = lane >> 4, l16 = lane & 15;

    const int id    = blockIdx.x;
    const int xcd   = id & 7;
    const int r     = id >> 3;            // 0..127
    const int head  = (r >> 4) * 8 + xcd; // stride-8 head map
    const int rem   = r & 15;
    const int qtile = rem >> 1;
    const int sp    = rem & 1;
    const int b = head >> 4, h = head & 15;
    const int s0 = qtile * 128;

    const float lam = 10.0f * __expf(-5.0f * u_prev[b]);
    const bool sparse = (lam >= 1.0f);

    const size_t bh = (size_t)b * NH + h;
    const ushort* Qh  = Qb + bh * NS * NDH;
    const ushort* Kh  = Kb + bh * NS * NDH;
    const ushort* Vh  = Vb + bh * NS * NDH;
    const ushort* Vth = Vt + bh * NDH * NS;

    if (!sparse) {
        const int kt0 = sp * 8;
        // stage mask words: 128 rows x 8 words for this split (8 KB)
#pragma unroll
        for (int u = 0; u < 4; ++u) {
            int idx = u * 256 + tid;
            MW[idx] = bm[(size_t)(s0 + (idx >> 3)) * 16 + kt0 + (idx & 7)];
        }

        bf16x8 qf[2][2];
#pragma unroll
        for (int qh = 0; qh < 2; ++qh)
#pragma unroll
            for (int kk = 0; kk < 2; ++kk)
                qf[qh][kk] = *(const bf16x8*)
                    &Qh[(size_t)(s0 + w*32 + qh*16 + l16) * NDH + kk*32 + quad*8];

        union { bf16x8 v; ushort s[8]; } ones;
#pragma unroll
        for (int i = 0; i < 8; ++i) ones.s[i] = 0x3F80;  // bf16 1.0

        f32x4 o_acc[2][4] = {};
        f32x4 l_acc[2] = {};

        const int sl = tid >> 2, c0 = (tid & 3) * 16;

        bf16x8 kreg[2], vreg[2];
        {
            const ushort* ksrc = &Kh[(size_t)(kt0*64 + sl) * NDH + c0];
            kreg[0] = *(const bf16x8*)ksrc;
            kreg[1] = *(const bf16x8*)(ksrc + 8);
            const ushort* vsrc = &Vth[(size_t)sl * NS + kt0*64 + c0];
            vreg[0] = *(const bf16x8*)vsrc;
            vreg[1] = *(const bf16x8*)(vsrc + 8);
        }

        for (int t = 0; t < 8; ++t) {
            const int kt = kt0 + t;
            __syncthreads();
            *(bf16x8*)&Ks[sl*72 + c0]      = kreg[0];
            *(bf16x8*)&Ks[sl*72 + c0 + 8]  = kreg[1];
            *(bf16x8*)&Vts[sl*72 + c0]     = vreg[0];
            *(bf16x8*)&Vts[sl*72 + c0 + 8] = vreg[1];
            __syncthreads();

            if (t < 7) {   // prefetch next tile; latency overlaps compute
                const ushort* ksrc = &Kh[(size_t)((kt+1)*64 + sl) * NDH + c0];
                kreg[0] = *(const bf16x8*)ksrc;
                kreg[1] = *(const bf16x8*)(ksrc + 8);
                const ushort* vsrc = &Vth[(size_t)sl * NS + (kt+1)*64 + c0];
                vreg[0] = *(const bf16x8*)vsrc;
                vreg[1] = *(const bf16x8*)(vsrc + 8);
            }

            // hoisted K/V fragments (shared by both qh groups)
            bf16x8 kf[4][2], vf[4][2];
#pragma unroll
            for (int nt = 0; nt < 4; ++nt)
#pragma unroll
                for (int kk = 0; kk < 2; ++kk) {
                    kf[nt][kk] = *(const bf16x8*)&Ks[(nt*16 + l16)*72 + kk*32 + quad*8];
                    vf[nt][kk] = *(const bf16x8*)&Vts[(nt*16 + l16)*72 + kk*32 + quad*8];
                }

#pragma unroll
            for (int qh = 0; qh < 2; ++qh) {
                f32x4 s_acc[4] = {};
#pragma unroll
                for (int nt = 0; nt < 4; ++nt)
#pragma unroll
                    for (int kk = 0; kk < 2; ++kk)
                        s_acc[nt] = __builtin_amdgcn_mfma_f32_16x16x32_bf16(
                            qf[qh][kk], kf[nt][kk], s_acc[nt], 0, 0, 0);

                u64 wv[4];
#pragma unroll
                for (int rg = 0; rg < 4; ++rg)
                    wv[rg] = MW[(w*32 + qh*16 + quad*4 + rg) * 8 + t];
#pragma unroll
                for (int nt = 0; nt < 4; ++nt)
#pragma unroll
                    for (int rg = 0; rg < 4; ++rg) {
                        float bias = ((wv[rg] >> (nt*16 + l16)) & 1ULL) ? 0.f : -lam;
                        float p = __expf(fmaf(s_acc[nt][rg], SCALE, bias));
                        Ps[(w*32 + qh*16 + quad*4 + rg) * 72 + nt*16 + l16] = f2bf(p);
                    }

                bf16x8 pf[2];
#pragma unroll
                for (int kk = 0; kk < 2; ++kk)
                    pf[kk] = *(const bf16x8*)&Ps[(w*32 + qh*16 + l16)*72 + kk*32 + quad*8];
#pragma unroll
                for (int kk = 0; kk < 2; ++kk) {
                    l_acc[qh] = __builtin_amdgcn_mfma_f32_16x16x32_bf16(
                        pf[kk], ones.v, l_acc[qh], 0, 0, 0);
#pragma unroll
                    for (int nt = 0; nt < 4; ++nt)
                        o_acc[qh][nt] = __builtin_amdgcn_mfma_f32_16x16x32_bf16(
                            pf[kk], vf[nt][kk], o_acc[qh][nt], 0, 0, 0);
                }
            }
        }

        // epilogue: accumulate partials (pure sum thanks to no-max softmax)
#pragma unroll
        for (int qh = 0; qh < 2; ++qh) {
#pragma unroll
            for (int nt = 0; nt < 4; ++nt)
#pragma unroll
                for (int rg = 0; rg < 4; ++rg) {
                    int m = w*32 + qh*16 + quad*4 + rg;
                    atomicAdd(&Od[((size_t)b*NS + s0 + m)*ND + h*NDH + nt*16 + l16],
                              o_acc[qh][nt][rg]);
                }
            if (l16 == 0) {
#pragma unroll
                for (int rg = 0; rg < 4; ++rg) {
                    int m = w*32 + qh*16 + quad*4 + rg;
                    atomicAdd(&Lb[bh*NS + s0 + m], l_acc[qh][rg]);
                }
            }
        }
    } else {
        if (sp) return;   // one block per (head,qtile) handles sparse
        const int r2  = lane & 15;
        const int cg  = lane >> 4;
#pragma unroll
        for (int qh = 0; qh < 2; ++qh) {
            const int row = w*32 + qh*16 + r2;

            float qreg[64];
            {
                const ushort* qp = Qh + (size_t)(s0 + row) * NDH;
#pragma unroll
                for (int c = 0; c < 8; ++c) {
                    union { bf16x8 v; ushort s[8]; } qv;
                    qv.v = *(const bf16x8*)(qp + c*8);
#pragma unroll
                    for (int j = 0; j < 8; ++j) qreg[c*8 + j] = bf2f(qv.s[j]);
                }
            }

            float sc[8];
#pragma unroll
            for (int jj = 0; jj < 8; ++jj) {
                int j  = cg*8 + jj;
                int mv = pimask[(size_t)(s0+row)*NKSP + j];
                if (mv) {
                    int kv = pidx[(size_t)(s0+row)*NKSP + j];
                    const ushort* krow = &Kh[(size_t)kv * NDH];
                    float acc = 0.f;
#pragma unroll
                    for (int c = 0; c < 8; ++c) {
                        union { bf16x8 v; ushort s[8]; } kk;
                        kk.v = *(const bf16x8*)(krow + c*8);
#pragma unroll
                        for (int jb = 0; jb < 8; ++jb)
                            acc = fmaf(qreg[c*8 + jb], bf2f(kk.s[jb]), acc);
                    }
                    sc[jj] = acc * SCALE;
                } else {
                    sc[jj] = -INFINITY;
                }
            }
            float mt = sc[0];
#pragma unroll
            for (int jj = 1; jj < 8; ++jj) mt = fmaxf(mt, sc[jj]);
            mt = fmaxf(mt, __shfl_xor(mt, 16));
            mt = fmaxf(mt, __shfl_xor(mt, 32));

            float psum = 0.f;
#pragma unroll
            for (int jj = 0; jj < 8; ++jj) {
                float p = __expf(sc[jj] - mt);
                psum += p;
                Ps[row * 72 + cg*8 + jj] = f2bf(p);
            }
            psum += __shfl_xor(psum, 16);
            psum += __shfl_xor(psum, 32);

            float o[16];
#pragma unroll
            for (int i = 0; i < 16; ++i) o[i] = 0.f;

            for (int j = 0; j < 32; ++j) {
                float p = bf2f(Ps[row * 72 + j]);
                if (p != 0.f) {
                    int kv = pidx[(size_t)(s0+row)*NKSP + j];
                    const ushort* vrow = &Vh[(size_t)kv * NDH + cg*16];
#pragma unroll
                    for (int c = 0; c < 2; ++c) {
                        union { bf16x8 v; ushort s[8]; } vv;
                        vv.v = *(const bf16x8*)(vrow + c*8);
#pragma unroll
                        for (int jb = 0; jb < 8; ++jb)
                            o[c*8 + jb] = fmaf(p, bf2f(vv.s[jb]), o[c*8 + jb]);
                    }
                }
            }

            float inv = 1.f / psum;
            ushort* op = OA + ((size_t)b*NS + s0 + row)*ND + h*NDH + cg*16;
#pragma unroll
            for (int i4 = 0; i4 < 4; ++i4) {
                ushort4 v;
                v.x = f2bf(o[i4*4+0]*inv); v.y = f2bf(o[i4*4+1]*inv);
                v.z = f2bf(o[i4*4+2]*inv); v.w = f2bf(o[i4*4+3]*inv);
                *(ushort4*)(op + i4*4) = v;
            }
        }
    }
}

// ---------------------------------------------------------------------------
// Normalize dense-batch rows: Awb = Od / Lb (bf16). Sparse rows already
// written by attn_split. Grid 4096 (one (b,s) row per block), 256 threads.
// ---------------------------------------------------------------------------
__global__ __launch_bounds__(256)
void norm_attn(const float* __restrict__ Od, const float* __restrict__ Lb,
               const float* __restrict__ u_prev, ushort* __restrict__ OA)
{
    int bs = blockIdx.x;
    int b = bs >> 10, s = bs & (NS - 1);
    float lam = 10.0f * __expf(-5.0f * u_prev[b]);
    if (lam >= 1.0f) return;   // sparse batch: already written
    int c = threadIdx.x * 4;
    int h = c >> 6;
    float inv = 1.f / Lb[((size_t)b*NH + h)*NS + s];
    float4 v = *(const float4*)&Od[((size_t)b*NS + s)*ND + c];
    ushort4 o;
    o.x = f2bf(v.x*inv); o.y = f2bf(v.y*inv);
    o.z = f2bf(v.z*inv); o.w = f2bf(v.w*inv);
    *(ushort4*)&OA[((size_t)b*NS + s)*ND + c] = o;
}

// ---------------------------------------------------------------------------
extern "C" void kernel_launch(void* const* d_in, const int* in_sizes, int n_in,
                              void* d_out, int out_size, void* d_ws, size_t ws_size,
                              hipStream_t stream)
{
    const float* x      = (const float*)d_in[0];
    const int*   pmask  = (const int*)  d_in[1];
    const int*   pidx   = (const int*)  d_in[2];
    const int*   pimask = (const int*)  d_in[3];
    const float* u_prev = (const float*)d_in[4];
    const float* Wq     = (const float*)d_in[5];
    const float* bq     = (const float*)d_in[6];
    const float* Wk     = (const float*)d_in[7];
    const float* bk     = (const float*)d_in[8];
    const float* Wv     = (const float*)d_in[9];
    const float* bv     = (const float*)d_in[10];
    const float* Wo     = (const float*)d_in[11];
    const float* bo     = (const float*)d_in[12];
    float* out = (float*)d_out;

    const size_t QSZ = (size_t)NB * NH * NS * NDH;   // 4,194,304 elements
    const size_t WSZ = (size_t)ND * ND;              // 1,048,576 elements
    ushort* xb  = (ushort*)d_ws;        // bf16 x              (8 MB)
    ushort* Qw  = xb  + QSZ;            // bf16 Q (b,h,s,dh)   (8 MB)
    ushort* Kw  = Qw  + QSZ;            // bf16 K              (8 MB)
    ushort* Vw  = Kw  + QSZ;            // bf16 V              (8 MB)
    ushort* Vtw = Vw  + QSZ;            // bf16 V^T (b,h,dh,s) (8 MB)
    ushort* Awb = Vtw + QSZ;            // bf16 attn out       (8 MB)
    ushort* Wqb = Awb + QSZ;            // bf16 weights (2 MB each)
    ushort* Wkb = Wqb + WSZ;
    ushort* Wvb = Wkb + WSZ;
    ushort* Wob = Wvb + WSZ;
    u64*    bmw = (u64*)(Wob + WSZ);    // packed mask (128 KB)
    float*  Lb  = (float*)(bmw + NS*16);// lsum accumulator (256 KB)
    // d_out (16 MB fp32) doubles as the unnormalized dense-o accumulator.

    hipMemsetAsync(d_out, 0, (size_t)out_size * sizeof(float), stream);
    hipMemsetAsync(Lb, 0, (size_t)NB * NH * NS * sizeof(float), stream);

    f2bf_multi<<<dim3(4096, 6), 256, 0, stream>>>(
        x, Wq, Wk, Wv, Wo, pmask, xb, Wqb, Wkb, Wvb, Wob, bmw);

    gemm_qkv<<<dim3(24, 32), 256, 0, stream>>>(
        xb, Wqb, Wkb, Wvb, bq, bk, bv, Qw, Kw, Vw, Vtw);

    attn_split<<<1024, 256, 0, stream>>>(
        Qw, Kw, Vw, Vtw, bmw, pidx, pimask, u_prev, (float*)d_out, Lb, Awb);

    norm_attn<<<4096, 256, 0, stream>>>((const float*)d_out, Lb, u_prev, Awb);

    gemm_out<<<dim3(ND/128, (NB*NS)/64), 256, 0, stream>>>(Awb, Wob, bo, out);
}

// Round 9
// 237.330 us; speedup vs baseline: 1.2618x; 1.2618x over previous
//
#include <hip/hip_runtime.h>
#include <hip/hip_bf16.h>
#include <cmath>

#define NB 4
#define NS 1024
#define ND 1024
#define NH 16
#define NDH 64
#define NKSP 32
#define SCALE 0.125f   // 1/sqrt(64)

typedef __attribute__((ext_vector_type(8))) short bf16x8;
typedef __attribute__((ext_vector_type(4))) float f32x4;
typedef unsigned long long u64;

#define AS1 __attribute__((address_space(1)))
#define AS3 __attribute__((address_space(3)))

__device__ __forceinline__ void gl_lds16(const void* g, void* l) {
    __builtin_amdgcn_global_load_lds((const AS1 void*)g, (AS3 void*)l, 16, 0, 0);
}

__device__ __forceinline__ ushort f2bf(float f) {
    union { __hip_bfloat16 h; ushort u; } cv;
    cv.h = __float2bfloat16(f);
    return cv.u;
}
__device__ __forceinline__ float bf2f(ushort u) {
    union { unsigned int i; float f; } cv;
    cv.i = ((unsigned int)u) << 16;
    return cv.f;
}

// ---------------------------------------------------------------------------
// y=0: x->bf16 (4096 blocks); y=1..4: W->bf16 (1024 blocks);
// y=5: pack pmask into bitwords (4096 blocks, one wave per u64 word).
// ---------------------------------------------------------------------------
__global__ __launch_bounds__(256)
void f2bf_multi(const float* __restrict__ x,
                const float* __restrict__ w0, const float* __restrict__ w1,
                const float* __restrict__ w2, const float* __restrict__ w3,
                const int* __restrict__ pm,
                ushort* __restrict__ xo,
                ushort* __restrict__ o0, ushort* __restrict__ o1,
                ushort* __restrict__ o2, ushort* __restrict__ o3,
                u64* __restrict__ bm)
{
    int y = blockIdx.y;
    if (y == 5) {
        int word = blockIdx.x * 4 + (threadIdx.x >> 6);
        int lane = threadIdx.x & 63;
        int row  = word >> 4, wcol = word & 15;
        int v = pm[(size_t)row * NS + wcol * 64 + lane];
        u64 b = __ballot(v != 0);
        if (lane == 0) bm[word] = b;
        return;
    }
    const float* src; ushort* dst; int nblk;
    if (y == 0)      { src = x;  dst = xo; nblk = 4096; }
    else if (y == 1) { src = w0; dst = o0; nblk = 1024; }
    else if (y == 2) { src = w1; dst = o1; nblk = 1024; }
    else if (y == 3) { src = w2; dst = o2; nblk = 1024; }
    else             { src = w3; dst = o3; nblk = 1024; }
    if (blockIdx.x >= (unsigned)nblk) return;
    int i = (blockIdx.x * 256 + threadIdx.x) * 4;
    float4 v = *(const float4*)&src[i];
    ushort4 o;
    o.x = f2bf(v.x); o.y = f2bf(v.y); o.z = f2bf(v.z); o.w = f2bf(v.w);
    *(ushort4*)&dst[i] = o;
}

// ---------------------------------------------------------------------------
// Fused QKV GEMM (direct-scatter epilogue; V also writes Vt).
// grid (24,32): blockIdx.x: [0,8)=Q [8,16)=K [16,24)=V.
// ---------------------------------------------------------------------------
__global__ __launch_bounds__(256)
void gemm_qkv(const ushort* __restrict__ xb,
              const ushort* __restrict__ Wqb, const ushort* __restrict__ Wkb,
              const ushort* __restrict__ Wvb,
              const float* __restrict__ bq, const float* __restrict__ bk,
              const float* __restrict__ bv,
              ushort* __restrict__ Qo, ushort* __restrict__ Ko,
              ushort* __restrict__ Vo, ushort* __restrict__ Vto)
{
    constexpr int K = ND;
    __shared__ __attribute__((aligned(16))) ushort As[128 * 32];
    __shared__ __attribute__((aligned(16))) ushort Bs[128 * 32];

    const int tid  = threadIdx.x;
    const int lane = tid & 63, w = tid >> 6;
    const int wm = w >> 1, wn = w & 1;
    const int which = blockIdx.x >> 3;
    const int n0 = (blockIdx.x & 7) * 128;
    const int m0 = blockIdx.y * 128;
    const int quad = lane >> 4, l16 = lane & 15;

    const ushort* W = (which == 0) ? Wqb : (which == 1) ? Wkb : Wvb;
    const float* bias = (which == 0) ? bq : (which == 1) ? bk : bv;
    ushort* Out = (which == 0) ? Qo : (which == 1) ? Ko : Vo;

    f32x4 acc[4][4] = {};

    for (int k0 = 0; k0 < K; k0 += 32) {
        __syncthreads();
#pragma unroll
        for (int u = 0; u < 2; ++u) {
            int t0 = u * 256 + w * 64;
            int t  = t0 + lane;
            int row = t >> 2, kc = (t & 3) * 8;
            gl_lds16(xb + (size_t)(m0 + row) * K + k0 + kc, &As[t0 * 8]);
            gl_lds16(W  + (size_t)(n0 + row) * K + k0 + kc, &Bs[t0 * 8]);
        }
        __syncthreads();

        bf16x8 af[4], bfr[4];
#pragma unroll
        for (int mt = 0; mt < 4; ++mt)
            af[mt] = *(const bf16x8*)&As[(wm*64 + mt*16 + l16) * 32 + quad*8];
#pragma unroll
        for (int nt = 0; nt < 4; ++nt)
            bfr[nt] = *(const bf16x8*)&Bs[(wn*64 + nt*16 + l16) * 32 + quad*8];
#pragma unroll
        for (int mt = 0; mt < 4; ++mt)
#pragma unroll
            for (int nt = 0; nt < 4; ++nt)
                acc[mt][nt] = __builtin_amdgcn_mfma_f32_16x16x32_bf16(
                    af[mt], bfr[nt], acc[mt][nt], 0, 0, 0);
    }

#pragma unroll
    for (int nt = 0; nt < 4; ++nt) {
        int n = n0 + wn*64 + nt*16 + l16;
        float bz = bias[n];
        int hh = n >> 6, dh = n & 63;
#pragma unroll
        for (int mt = 0; mt < 4; ++mt) {
#pragma unroll
            for (int rg = 0; rg < 4; ++rg) {
                int m = m0 + wm*64 + mt*16 + quad*4 + rg;
                int b = m >> 10, s = m & (NS - 1);
                ushort val = f2bf(acc[mt][nt][rg] + bz);
                Out[(((size_t)(b*NH + hh))*NS + s)*NDH + dh] = val;
                if (which == 2)
                    Vto[(((size_t)(b*NH + hh))*NDH + dh)*NS + s] = val;
            }
        }
    }
}

// ---------------------------------------------------------------------------
// Output GEMM: 64x128 tile -> 512 blocks.
// ---------------------------------------------------------------------------
__global__ __launch_bounds__(256)
void gemm_out(const ushort* __restrict__ A, const ushort* __restrict__ W,
              const float* __restrict__ bias, float* __restrict__ Cout)
{
    constexpr int K = ND;
    __shared__ __attribute__((aligned(16))) ushort As[64 * 32];
    __shared__ __attribute__((aligned(16))) ushort Bs[128 * 32];

    const int tid  = threadIdx.x;
    const int lane = tid & 63, w = tid >> 6;
    const int wm = w & 1, wn = w >> 1;
    const int m0 = blockIdx.y * 64, n0 = blockIdx.x * 128;
    const int quad = lane >> 4, l16 = lane & 15;

    f32x4 acc[2][4] = {};

    for (int k0 = 0; k0 < K; k0 += 32) {
        __syncthreads();
        {
            int t0 = w * 64;
            int t  = t0 + lane;
            int row = t >> 2, kc = (t & 3) * 8;
            gl_lds16(A + (size_t)(m0 + row) * K + k0 + kc, &As[t0 * 8]);
        }
#pragma unroll
        for (int u = 0; u < 2; ++u) {
            int t0 = u * 256 + w * 64;
            int t  = t0 + lane;
            int row = t >> 2, kc = (t & 3) * 8;
            gl_lds16(W + (size_t)(n0 + row) * K + k0 + kc, &Bs[t0 * 8]);
        }
        __syncthreads();

        bf16x8 af[2], bfr[4];
#pragma unroll
        for (int mt = 0; mt < 2; ++mt)
            af[mt] = *(const bf16x8*)&As[(wm*32 + mt*16 + l16) * 32 + quad*8];
#pragma unroll
        for (int nt = 0; nt < 4; ++nt)
            bfr[nt] = *(const bf16x8*)&Bs[(wn*64 + nt*16 + l16) * 32 + quad*8];
#pragma unroll
        for (int mt = 0; mt < 2; ++mt)
#pragma unroll
            for (int nt = 0; nt < 4; ++nt)
                acc[mt][nt] = __builtin_amdgcn_mfma_f32_16x16x32_bf16(
                    af[mt], bfr[nt], acc[mt][nt], 0, 0, 0);
    }

#pragma unroll
    for (int nt = 0; nt < 4; ++nt) {
        int n = n0 + wn*64 + nt*16 + l16;
        float bz = bias[n];
#pragma unroll
        for (int mt = 0; mt < 2; ++mt) {
#pragma unroll
            for (int rg = 0; rg < 4; ++rg) {
                int m = m0 + wm*32 + mt*16 + quad*4 + rg;
                Cout[(size_t)m * ND + n] = acc[mt][nt][rg] + bz;
            }
        }
    }
}

// ---------------------------------------------------------------------------
// MFMA flash attention, 128 q-rows/block, grid 512.
// Block map: xcd = id&7; t = id>>3; qtile = t&7; head = (t>>3)*8 + xcd.
// -> q-tiles of a head share an XCD (K/Vt L2-local) AND every batch's heads
// spread over all 8 XCDs (dense work always balanced).
// Dense: S^T trick — mfma(kf, qf) gives C-layout row=key, col=query, so a
// lane's 4 rg values are 4 CONSECUTIVE j's of one P row -> ds_write_b64
// (4 writes/qh vs 16 scalar), and 1 mask-word load/qh (row = l16).
// pf/vf/PV/lsum/epilogue layouts unchanged. No max subtraction (scores
// bounded); lsum via ones-MFMA. Sparse: scalar fp32, 32 gathered keys.
// LDS = 9216*2 + 18432 + 16384 = 53248 B -> 3 blocks/CU.
// ---------------------------------------------------------------------------
__global__ __launch_bounds__(256)
void attn_kernel(const ushort* __restrict__ Qb, const ushort* __restrict__ Kb,
                 const ushort* __restrict__ Vb, const ushort* __restrict__ Vt,
                 const u64* __restrict__ bm,
                 const int* __restrict__ pidx, const int* __restrict__ pimask,
                 const float* __restrict__ u_prev, ushort* __restrict__ OA)
{
    __shared__ __attribute__((aligned(16))) ushort Ks[64 * 72];
    __shared__ __attribute__((aligned(16))) ushort Vts[64 * 72];
    __shared__ __attribute__((aligned(16))) ushort Ps[128 * 72];
    __shared__ __attribute__((aligned(16))) u64    MW[128 * 16];

    const int tid  = threadIdx.x;
    const int lane = tid & 63, w = tid >> 6;
    const int quad = lane >> 4, l16 = lane & 15;

    const int id    = blockIdx.x;
    const int xcd   = id & 7;
    const int t5    = id >> 3;            // 0..63
    const int qtile = t5 & 7;
    const int head  = (t5 >> 3) * 8 + xcd;
    const int b = head >> 4, h = head & 15;
    const int s0 = qtile * 128;

    const float lam = 10.0f * __expf(-5.0f * u_prev[b]);
    const bool sparse = (lam >= 1.0f);

    const size_t bh = (size_t)b * NH + h;
    const ushort* Qh  = Qb + bh * NS * NDH;
    const ushort* Kh  = Kb + bh * NS * NDH;
    const ushort* Vh  = Vb + bh * NS * NDH;
    const ushort* Vth = Vt + bh * NDH * NS;

    if (!sparse) {
        // stage mask words for rows s0..s0+127 (2048 u64 = 16 KB)
#pragma unroll
        for (int u = 0; u < 8; ++u) {
            int idx = u * 256 + tid;
            MW[idx] = bm[(size_t)s0 * 16 + idx];
        }

        // Q fragments (serve as B-operand = Q^T; same memory pattern)
        bf16x8 qf[2][2];
#pragma unroll
        for (int qh = 0; qh < 2; ++qh)
#pragma unroll
            for (int kk = 0; kk < 2; ++kk)
                qf[qh][kk] = *(const bf16x8*)
                    &Qh[(size_t)(s0 + w*32 + qh*16 + l16) * NDH + kk*32 + quad*8];

        union { bf16x8 v; ushort s[8]; } ones;
#pragma unroll
        for (int i = 0; i < 8; ++i) ones.s[i] = 0x3F80;  // bf16 1.0

        f32x4 o_acc[2][4] = {};
        f32x4 l_acc[2] = {};

        const int sl = tid >> 2, c0 = (tid & 3) * 16;

        // prefetch tile 0 into regs
        bf16x8 kreg[2], vreg[2];
        {
            const ushort* ksrc = &Kh[(size_t)sl * NDH + c0];
            kreg[0] = *(const bf16x8*)ksrc;
            kreg[1] = *(const bf16x8*)(ksrc + 8);
            const ushort* vsrc = &Vth[(size_t)sl * NS + c0];
            vreg[0] = *(const bf16x8*)vsrc;
            vreg[1] = *(const bf16x8*)(vsrc + 8);
        }

        for (int kt = 0; kt < 16; ++kt) {
            __syncthreads();
            *(bf16x8*)&Ks[sl*72 + c0]      = kreg[0];
            *(bf16x8*)&Ks[sl*72 + c0 + 8]  = kreg[1];
            *(bf16x8*)&Vts[sl*72 + c0]     = vreg[0];
            *(bf16x8*)&Vts[sl*72 + c0 + 8] = vreg[1];
            __syncthreads();

            if (kt < 15) {   // prefetch next tile; latency overlaps compute
                const ushort* ksrc = &Kh[(size_t)((kt+1)*64 + sl) * NDH + c0];
                kreg[0] = *(const bf16x8*)ksrc;
                kreg[1] = *(const bf16x8*)(ksrc + 8);
                const ushort* vsrc = &Vth[(size_t)sl * NS + (kt+1)*64 + c0];
                vreg[0] = *(const bf16x8*)vsrc;
                vreg[1] = *(const bf16x8*)(vsrc + 8);
            }

            // hoisted K/V fragments (shared by both qh groups)
            bf16x8 kf[4][2], vf[4][2];
#pragma unroll
            for (int nt = 0; nt < 4; ++nt)
#pragma unroll
                for (int kk = 0; kk < 2; ++kk) {
                    kf[nt][kk] = *(const bf16x8*)&Ks[(nt*16 + l16)*72 + kk*32 + quad*8];
                    vf[nt][kk] = *(const bf16x8*)&Vts[(nt*16 + l16)*72 + kk*32 + quad*8];
                }

#pragma unroll
            for (int qh = 0; qh < 2; ++qh) {
                const int qrow = w*32 + qh*16 + l16;   // this lane's query

                // S^T: mfma(K-frag, Q-frag) -> row=key_local, col=query
                f32x4 s_acc[4] = {};
#pragma unroll
                for (int nt = 0; nt < 4; ++nt)
#pragma unroll
                    for (int kk = 0; kk < 2; ++kk)
                        s_acc[nt] = __builtin_amdgcn_mfma_f32_16x16x32_bf16(
                            kf[nt][kk], qf[qh][kk], s_acc[nt], 0, 0, 0);

                // mask (1 word/lane) + scale + exp; P row-major via b64 writes
                u64 wq = MW[qrow * 16 + kt] >> (quad * 4);
#pragma unroll
                for (int nt = 0; nt < 4; ++nt) {
                    ushort4 pk;
                    float p0, p1, p2, p3;
                    p0 = __expf(fmaf(s_acc[nt][0], SCALE,
                         ((wq >> (nt*16 + 0)) & 1ULL) ? 0.f : -lam));
                    p1 = __expf(fmaf(s_acc[nt][1], SCALE,
                         ((wq >> (nt*16 + 1)) & 1ULL) ? 0.f : -lam));
                    p2 = __expf(fmaf(s_acc[nt][2], SCALE,
                         ((wq >> (nt*16 + 2)) & 1ULL) ? 0.f : -lam));
                    p3 = __expf(fmaf(s_acc[nt][3], SCALE,
                         ((wq >> (nt*16 + 3)) & 1ULL) ? 0.f : -lam));
                    pk.x = f2bf(p0); pk.y = f2bf(p1);
                    pk.z = f2bf(p2); pk.w = f2bf(p3);
                    *(ushort4*)&Ps[qrow*72 + nt*16 + quad*4] = pk;
                }

                // PV + lsum (wave-internal P round-trip; no barrier)
                bf16x8 pf[2];
#pragma unroll
                for (int kk = 0; kk < 2; ++kk)
                    pf[kk] = *(const bf16x8*)&Ps[qrow*72 + kk*32 + quad*8];
#pragma unroll
                for (int kk = 0; kk < 2; ++kk) {
                    l_acc[qh] = __builtin_amdgcn_mfma_f32_16x16x32_bf16(
                        pf[kk], ones.v, l_acc[qh], 0, 0, 0);
#pragma unroll
                    for (int nt = 0; nt < 4; ++nt)
                        o_acc[qh][nt] = __builtin_amdgcn_mfma_f32_16x16x32_bf16(
                            pf[kk], vf[nt][kk], o_acc[qh][nt], 0, 0, 0);
                }
            }
        }

        // epilogue (o_acc: row=query quad*4+rg, col=dh nt*16+l16)
#pragma unroll
        for (int qh = 0; qh < 2; ++qh) {
            float inv[4];
#pragma unroll
            for (int rg = 0; rg < 4; ++rg) inv[rg] = 1.f / l_acc[qh][rg];
#pragma unroll
            for (int nt = 0; nt < 4; ++nt)
#pragma unroll
                for (int rg = 0; rg < 4; ++rg) {
                    int m = w*32 + qh*16 + quad*4 + rg;
                    OA[((size_t)b*NS + s0 + m)*ND + h*NDH + nt*16 + l16] =
                        f2bf(o_acc[qh][nt][rg] * inv[rg]);
                }
        }
    } else {
        // ---------------- sparse path (fp32 scalar, bf16 inputs) ----------
        const int r2  = lane & 15;
        const int cg  = lane >> 4;
#pragma unroll
        for (int qh = 0; qh < 2; ++qh) {
            const int row = w*32 + qh*16 + r2;

            float qreg[64];
            {
                const ushort* qp = Qh + (size_t)(s0 + row) * NDH;
#pragma unroll
                for (int c = 0; c < 8; ++c) {
                    union { bf16x8 v; ushort s[8]; } qv;
                    qv.v = *(const bf16x8*)(qp + c*8);
#pragma unroll
                    for (int j = 0; j < 8; ++j) qreg[c*8 + j] = bf2f(qv.s[j]);
                }
            }

            float sc[8];
#pragma unroll
            for (int jj = 0; jj < 8; ++jj) {
                int j  = cg*8 + jj;
                int mv = pimask[(size_t)(s0+row)*NKSP + j];
                if (mv) {
                    int kv = pidx[(size_t)(s0+row)*NKSP + j];
                    const ushort* krow = &Kh[(size_t)kv * NDH];
                    float acc = 0.f;
#pragma unroll
                    for (int c = 0; c < 8; ++c) {
                        union { bf16x8 v; ushort s[8]; } kk;
                        kk.v = *(const bf16x8*)(krow + c*8);
#pragma unroll
                        for (int jb = 0; jb < 8; ++jb)
                            acc = fmaf(qreg[c*8 + jb], bf2f(kk.s[jb]), acc);
                    }
                    sc[jj] = acc * SCALE;
                } else {
                    sc[jj] = -INFINITY;
                }
            }
            float mt = sc[0];
#pragma unroll
            for (int jj = 1; jj < 8; ++jj) mt = fmaxf(mt, sc[jj]);
            mt = fmaxf(mt, __shfl_xor(mt, 16));
            mt = fmaxf(mt, __shfl_xor(mt, 32));

            float psum = 0.f;
#pragma unroll
            for (int jj = 0; jj < 8; ++jj) {
                float p = __expf(sc[jj] - mt);
                psum += p;
                Ps[row * 72 + cg*8 + jj] = f2bf(p);
            }
            psum += __shfl_xor(psum, 16);
            psum += __shfl_xor(psum, 32);

            float o[16];
#pragma unroll
            for (int i = 0; i < 16; ++i) o[i] = 0.f;

            for (int j = 0; j < 32; ++j) {
                float p = bf2f(Ps[row * 72 + j]);
                if (p != 0.f) {
                    int kv = pidx[(size_t)(s0+row)*NKSP + j];
                    const ushort* vrow = &Vh[(size_t)kv * NDH + cg*16];
#pragma unroll
                    for (int c = 0; c < 2; ++c) {
                        union { bf16x8 v; ushort s[8]; } vv;
                        vv.v = *(const bf16x8*)(vrow + c*8);
#pragma unroll
                        for (int jb = 0; jb < 8; ++jb)
                            o[c*8 + jb] = fmaf(p, bf2f(vv.s[jb]), o[c*8 + jb]);
                    }
                }
            }

            float inv = 1.f / psum;
            ushort* op = OA + ((size_t)b*NS + s0 + row)*ND + h*NDH + cg*16;
#pragma unroll
            for (int i4 = 0; i4 < 4; ++i4) {
                ushort4 v;
                v.x = f2bf(o[i4*4+0]*inv); v.y = f2bf(o[i4*4+1]*inv);
                v.z = f2bf(o[i4*4+2]*inv); v.w = f2bf(o[i4*4+3]*inv);
                *(ushort4*)(op + i4*4) = v;
            }
        }
    }
}

// ---------------------------------------------------------------------------
extern "C" void kernel_launch(void* const* d_in, const int* in_sizes, int n_in,
                              void* d_out, int out_size, void* d_ws, size_t ws_size,
                              hipStream_t stream)
{
    const float* x      = (const float*)d_in[0];
    const int*   pmask  = (const int*)  d_in[1];
    const int*   pidx   = (const int*)  d_in[2];
    const int*   pimask = (const int*)  d_in[3];
    const float* u_prev = (const float*)d_in[4];
    const float* Wq     = (const float*)d_in[5];
    const float* bq     = (const float*)d_in[6];
    const float* Wk     = (const float*)d_in[7];
    const float* bk     = (const float*)d_in[8];
    const float* Wv     = (const float*)d_in[9];
    const float* bv     = (const float*)d_in[10];
    const float* Wo     = (const float*)d_in[11];
    const float* bo     = (const float*)d_in[12];
    float* out = (float*)d_out;

    const size_t QSZ = (size_t)NB * NH * NS * NDH;   // 4,194,304 elements
    const size_t WSZ = (size_t)ND * ND;              // 1,048,576 elements
    ushort* xb  = (ushort*)d_ws;        // bf16 x              (8 MB)
    ushort* Qw  = xb  + QSZ;            // bf16 Q (b,h,s,dh)   (8 MB)
    ushort* Kw  = Qw  + QSZ;            // bf16 K              (8 MB)
    ushort* Vw  = Kw  + QSZ;            // bf16 V              (8 MB)
    ushort* Vtw = Vw  + QSZ;            // bf16 V^T (b,h,dh,s) (8 MB)
    ushort* Awb = Vtw + QSZ;            // bf16 attn out       (8 MB)
    ushort* Wqb = Awb + QSZ;            // bf16 weights (2 MB each)
    ushort* Wkb = Wqb + WSZ;
    ushort* Wvb = Wkb + WSZ;
    ushort* Wob = Wvb + WSZ;
    u64*    bmw = (u64*)(Wob + WSZ);    // packed mask (128 KB)

    f2bf_multi<<<dim3(4096, 6), 256, 0, stream>>>(
        x, Wq, Wk, Wv, Wo, pmask, xb, Wqb, Wkb, Wvb, Wob, bmw);

    gemm_qkv<<<dim3(24, 32), 256, 0, stream>>>(
        xb, Wqb, Wkb, Wvb, bq, bk, bv, Qw, Kw, Vw, Vtw);

    attn_kernel<<<512, 256, 0, stream>>>(
        Qw, Kw, Vw, Vtw, bmw, pidx, pimask, u_prev, Awb);

    gemm_out<<<dim3(ND/128, (NB*NS)/64), 256, 0, stream>>>(Awb, Wob, bo, out);
}

// Round 11
// 236.186 us; speedup vs baseline: 1.2679x; 1.0048x over previous
//
#include <hip/hip_runtime.h>
#include <hip/hip_bf16.h>
#include <cmath>

#define NB 4
#define NS 1024
#define ND 1024
#define NH 16
#define NDH 64
#define NKSP 32
#define SCALE 0.125f      // 1/sqrt(64)
#define LOG2E 1.44269504f
#define SCALE2 (SCALE * LOG2E)

typedef __attribute__((ext_vector_type(8))) short bf16x8;
typedef __attribute__((ext_vector_type(4))) float f32x4;
typedef unsigned long long u64;

#define AS1 __attribute__((address_space(1)))
#define AS3 __attribute__((address_space(3)))

__device__ __forceinline__ void gl_lds16(const void* g, void* l) {
    __builtin_amdgcn_global_load_lds((const AS1 void*)g, (AS3 void*)l, 16, 0, 0);
}

__device__ __forceinline__ ushort f2bf(float f) {
    union { __hip_bfloat16 h; ushort u; } cv;
    cv.h = __float2bfloat16(f);
    return cv.u;
}
__device__ __forceinline__ float bf2f(ushort u) {
    union { unsigned int i; float f; } cv;
    cv.i = ((unsigned int)u) << 16;
    return cv.f;
}
__device__ __forceinline__ float fexp2(float x) {
    return __builtin_amdgcn_exp2f(x);   // v_exp_f32 (base-2)
}

// ---------------------------------------------------------------------------
// y=0: x->bf16 (4096 blocks); y=1..4: W->bf16 (1024 blocks);
// y=5: pack pmask into bitwords (4096 blocks, one wave per u64 word).
// ---------------------------------------------------------------------------
__global__ __launch_bounds__(256)
void f2bf_multi(const float* __restrict__ x,
                const float* __restrict__ w0, const float* __restrict__ w1,
                const float* __restrict__ w2, const float* __restrict__ w3,
                const int* __restrict__ pm,
                ushort* __restrict__ xo,
                ushort* __restrict__ o0, ushort* __restrict__ o1,
                ushort* __restrict__ o2, ushort* __restrict__ o3,
                u64* __restrict__ bm)
{
    int y = blockIdx.y;
    if (y == 5) {
        int word = blockIdx.x * 4 + (threadIdx.x >> 6);
        int lane = threadIdx.x & 63;
        int row  = word >> 4, wcol = word & 15;
        int v = pm[(size_t)row * NS + wcol * 64 + lane];
        u64 b = __ballot(v != 0);
        if (lane == 0) bm[word] = b;
        return;
    }
    const float* src; ushort* dst; int nblk;
    if (y == 0)      { src = x;  dst = xo; nblk = 4096; }
    else if (y == 1) { src = w0; dst = o0; nblk = 1024; }
    else if (y == 2) { src = w1; dst = o1; nblk = 1024; }
    else if (y == 3) { src = w2; dst = o2; nblk = 1024; }
    else             { src = w3; dst = o3; nblk = 1024; }
    if (blockIdx.x >= (unsigned)nblk) return;
    int i = (blockIdx.x * 256 + threadIdx.x) * 4;
    float4 v = *(const float4*)&src[i];
    ushort4 o;
    o.x = f2bf(v.x); o.y = f2bf(v.y); o.z = f2bf(v.z); o.w = f2bf(v.w);
    *(ushort4*)&dst[i] = o;
}

// ---------------------------------------------------------------------------
// Fused QKV GEMM (direct-scatter epilogue; V also writes Vt).
// grid (24,32): blockIdx.x: [0,8)=Q [8,16)=K [16,24)=V.
// ---------------------------------------------------------------------------
__global__ __launch_bounds__(256)
void gemm_qkv(const ushort* __restrict__ xb,
              const ushort* __restrict__ Wqb, const ushort* __restrict__ Wkb,
              const ushort* __restrict__ Wvb,
              const float* __restrict__ bq, const float* __restrict__ bk,
              const float* __restrict__ bv,
              ushort* __restrict__ Qo, ushort* __restrict__ Ko,
              ushort* __restrict__ Vo, ushort* __restrict__ Vto)
{
    constexpr int K = ND;
    __shared__ __attribute__((aligned(16))) ushort As[128 * 32];
    __shared__ __attribute__((aligned(16))) ushort Bs[128 * 32];

    const int tid  = threadIdx.x;
    const int lane = tid & 63, w = tid >> 6;
    const int wm = w >> 1, wn = w & 1;
    const int which = blockIdx.x >> 3;
    const int n0 = (blockIdx.x & 7) * 128;
    const int m0 = blockIdx.y * 128;
    const int quad = lane >> 4, l16 = lane & 15;

    const ushort* W = (which == 0) ? Wqb : (which == 1) ? Wkb : Wvb;
    const float* bias = (which == 0) ? bq : (which == 1) ? bk : bv;
    ushort* Out = (which == 0) ? Qo : (which == 1) ? Ko : Vo;

    f32x4 acc[4][4] = {};

    for (int k0 = 0; k0 < K; k0 += 32) {
        __syncthreads();
#pragma unroll
        for (int u = 0; u < 2; ++u) {
            int t0 = u * 256 + w * 64;
            int t  = t0 + lane;
            int row = t >> 2, kc = (t & 3) * 8;
            gl_lds16(xb + (size_t)(m0 + row) * K + k0 + kc, &As[t0 * 8]);
            gl_lds16(W  + (size_t)(n0 + row) * K + k0 + kc, &Bs[t0 * 8]);
        }
        __syncthreads();

        bf16x8 af[4], bfr[4];
#pragma unroll
        for (int mt = 0; mt < 4; ++mt)
            af[mt] = *(const bf16x8*)&As[(wm*64 + mt*16 + l16) * 32 + quad*8];
#pragma unroll
        for (int nt = 0; nt < 4; ++nt)
            bfr[nt] = *(const bf16x8*)&Bs[(wn*64 + nt*16 + l16) * 32 + quad*8];
#pragma unroll
        for (int mt = 0; mt < 4; ++mt)
#pragma unroll
            for (int nt = 0; nt < 4; ++nt)
                acc[mt][nt] = __builtin_amdgcn_mfma_f32_16x16x32_bf16(
                    af[mt], bfr[nt], acc[mt][nt], 0, 0, 0);
    }

#pragma unroll
    for (int nt = 0; nt < 4; ++nt) {
        int n = n0 + wn*64 + nt*16 + l16;
        float bz = bias[n];
        int hh = n >> 6, dh = n & 63;
#pragma unroll
        for (int mt = 0; mt < 4; ++mt) {
#pragma unroll
            for (int rg = 0; rg < 4; ++rg) {
                int m = m0 + wm*64 + mt*16 + quad*4 + rg;
                int b = m >> 10, s = m & (NS - 1);
                ushort val = f2bf(acc[mt][nt][rg] + bz);
                Out[(((size_t)(b*NH + hh))*NS + s)*NDH + dh] = val;
                if (which == 2)
                    Vto[(((size_t)(b*NH + hh))*NDH + dh)*NS + s] = val;
            }
        }
    }
}

// ---------------------------------------------------------------------------
// Output GEMM: 64x128 tile -> 512 blocks.
// ---------------------------------------------------------------------------
__global__ __launch_bounds__(256)
void gemm_out(const ushort* __restrict__ A, const ushort* __restrict__ W,
              const float* __restrict__ bias, float* __restrict__ Cout)
{
    constexpr int K = ND;
    __shared__ __attribute__((aligned(16))) ushort As[64 * 32];
    __shared__ __attribute__((aligned(16))) ushort Bs[128 * 32];

    const int tid  = threadIdx.x;
    const int lane = tid & 63, w = tid >> 6;
    const int wm = w & 1, wn = w >> 1;
    const int m0 = blockIdx.y * 64, n0 = blockIdx.x * 128;
    const int quad = lane >> 4, l16 = lane & 15;

    f32x4 acc[2][4] = {};

    for (int k0 = 0; k0 < K; k0 += 32) {
        __syncthreads();
        {
            int t0 = w * 64;
            int t  = t0 + lane;
            int row = t >> 2, kc = (t & 3) * 8;
            gl_lds16(A + (size_t)(m0 + row) * K + k0 + kc, &As[t0 * 8]);
        }
#pragma unroll
        for (int u = 0; u < 2; ++u) {
            int t0 = u * 256 + w * 64;
            int t  = t0 + lane;
            int row = t >> 2, kc = (t & 3) * 8;
            gl_lds16(W + (size_t)(n0 + row) * K + k0 + kc, &Bs[t0 * 8]);
        }
        __syncthreads();

        bf16x8 af[2], bfr[4];
#pragma unroll
        for (int mt = 0; mt < 2; ++mt)
            af[mt] = *(const bf16x8*)&As[(wm*32 + mt*16 + l16) * 32 + quad*8];
#pragma unroll
        for (int nt = 0; nt < 4; ++nt)
            bfr[nt] = *(const bf16x8*)&Bs[(wn*64 + nt*16 + l16) * 32 + quad*8];
#pragma unroll
        for (int mt = 0; mt < 2; ++mt)
#pragma unroll
            for (int nt = 0; nt < 4; ++nt)
                acc[mt][nt] = __builtin_amdgcn_mfma_f32_16x16x32_bf16(
                    af[mt], bfr[nt], acc[mt][nt], 0, 0, 0);
    }

#pragma unroll
    for (int nt = 0; nt < 4; ++nt) {
        int n = n0 + wn*64 + nt*16 + l16;
        float bz = bias[n];
#pragma unroll
        for (int mt = 0; mt < 2; ++mt) {
#pragma unroll
            for (int rg = 0; rg < 4; ++rg) {
                int m = m0 + wm*32 + mt*16 + quad*4 + rg;
                Cout[(size_t)m * ND + n] = acc[mt][nt][rg] + bz;
            }
        }
    }
}

// ---------------------------------------------------------------------------
// MFMA flash attention, 128 q-rows/block, grid 512.
// Block map: xcd = id&7; t = id>>3; qtile = t&7; head = (t>>3)*8 + xcd
// (q-tiles of a head share an XCD; every batch spreads over all 8 XCDs).
// Dense: NO LDS staging for K/V — fragments loaded straight from global
// (L2-hot per XCD; 4 waves read identical addresses -> L1 broadcast).
// Only ONE barrier (after MW staging); no per-tile barriers at all.
// S^T mfma(kf,qf) -> P row-major, b64 P writes; base-2 exp (constants
// folded); lsum via ones-MFMA; no max subtraction (scores bounded).
// Sparse: scalar fp32 over 32 gathered keys.
// LDS = Ps 18432 + MW 16384 = 34.8 KB.
// ---------------------------------------------------------------------------
__global__ __launch_bounds__(256)
void attn_kernel(const ushort* __restrict__ Qb, const ushort* __restrict__ Kb,
                 const ushort* __restrict__ Vb, const ushort* __restrict__ Vt,
                 const u64* __restrict__ bm,
                 const int* __restrict__ pidx, const int* __restrict__ pimask,
                 const float* __restrict__ u_prev, ushort* __restrict__ OA)
{
    __shared__ __attribute__((aligned(16))) ushort Ps[128 * 72];
    __shared__ __attribute__((aligned(16))) u64    MW[128 * 16];

    const int tid  = threadIdx.x;
    const int lane = tid & 63, w = tid >> 6;
    const int quad = lane >> 4, l16 = lane & 15;

    const int id    = blockIdx.x;
    const int xcd   = id & 7;
    const int t5    = id >> 3;            // 0..63
    const int qtile = t5 & 7;
    const int head  = (t5 >> 3) * 8 + xcd;
    const int b = head >> 4, h = head & 15;
    const int s0 = qtile * 128;

    const float lam = 10.0f * __expf(-5.0f * u_prev[b]);
    const bool sparse = (lam >= 1.0f);

    const size_t bh = (size_t)b * NH + h;
    const ushort* Qh  = Qb + bh * NS * NDH;
    const ushort* Kh  = Kb + bh * NS * NDH;
    const ushort* Vh  = Vb + bh * NS * NDH;
    const ushort* Vth = Vt + bh * NDH * NS;

    if (!sparse) {
        const float nlam2 = -lam * LOG2E;   // base-2 bias

        // stage mask words for rows s0..s0+127 (2048 u64 = 16 KB)
#pragma unroll
        for (int u = 0; u < 8; ++u) {
            int idx = u * 256 + tid;
            MW[idx] = bm[(size_t)s0 * 16 + idx];
        }
        __syncthreads();   // the only block barrier

        // Q fragments (serve as B-operand = Q^T)
        bf16x8 qf[2][2];
#pragma unroll
        for (int qh = 0; qh < 2; ++qh)
#pragma unroll
            for (int kk = 0; kk < 2; ++kk)
                qf[qh][kk] = *(const bf16x8*)
                    &Qh[(size_t)(s0 + w*32 + qh*16 + l16) * NDH + kk*32 + quad*8];

        union { bf16x8 v; ushort s[8]; } ones;
#pragma unroll
        for (int i = 0; i < 8; ++i) ones.s[i] = 0x3F80;  // bf16 1.0

        f32x4 o_acc[2][4] = {};
        f32x4 l_acc[2] = {};

        for (int kt = 0; kt < 16; ++kt) {
            // K/V fragments straight from global (identical across waves ->
            // L1 broadcast; tiles L2-resident via XCD swizzle)
            bf16x8 kf[4][2], vf[4][2];
#pragma unroll
            for (int nt = 0; nt < 4; ++nt)
#pragma unroll
                for (int kk = 0; kk < 2; ++kk) {
                    kf[nt][kk] = *(const bf16x8*)
                        &Kh[(size_t)(kt*64 + nt*16 + l16) * NDH + kk*32 + quad*8];
                    vf[nt][kk] = *(const bf16x8*)
                        &Vth[(size_t)(nt*16 + l16) * NS + kt*64 + kk*32 + quad*8];
                }

#pragma unroll
            for (int qh = 0; qh < 2; ++qh) {
                const int qrow = w*32 + qh*16 + l16;

                // S^T: mfma(K-frag, Q-frag) -> row=key_local, col=query
                f32x4 s_acc[4] = {};
#pragma unroll
                for (int nt = 0; nt < 4; ++nt)
#pragma unroll
                    for (int kk = 0; kk < 2; ++kk)
                        s_acc[nt] = __builtin_amdgcn_mfma_f32_16x16x32_bf16(
                            kf[nt][kk], qf[qh][kk], s_acc[nt], 0, 0, 0);

                // mask (1 word/lane) + base-2 exp; P row-major via b64 writes
                u64 wq = MW[qrow * 16 + kt] >> (quad * 4);
#pragma unroll
                for (int nt = 0; nt < 4; ++nt) {
                    ushort4 pk;
                    float p0 = fexp2(fmaf(s_acc[nt][0], SCALE2,
                         ((wq >> (nt*16 + 0)) & 1ULL) ? 0.f : nlam2));
                    float p1 = fexp2(fmaf(s_acc[nt][1], SCALE2,
                         ((wq >> (nt*16 + 1)) & 1ULL) ? 0.f : nlam2));
                    float p2 = fexp2(fmaf(s_acc[nt][2], SCALE2,
                         ((wq >> (nt*16 + 2)) & 1ULL) ? 0.f : nlam2));
                    float p3 = fexp2(fmaf(s_acc[nt][3], SCALE2,
                         ((wq >> (nt*16 + 3)) & 1ULL) ? 0.f : nlam2));
                    pk.x = f2bf(p0); pk.y = f2bf(p1);
                    pk.z = f2bf(p2); pk.w = f2bf(p3);
                    *(ushort4*)&Ps[qrow*72 + nt*16 + quad*4] = pk;
                }

                // PV + lsum (wave-internal P round-trip; no barrier)
                bf16x8 pf[2];
#pragma unroll
                for (int kk = 0; kk < 2; ++kk)
                    pf[kk] = *(const bf16x8*)&Ps[qrow*72 + kk*32 + quad*8];
#pragma unroll
                for (int kk = 0; kk < 2; ++kk) {
                    l_acc[qh] = __builtin_amdgcn_mfma_f32_16x16x32_bf16(
                        pf[kk], ones.v, l_acc[qh], 0, 0, 0);
#pragma unroll
                    for (int nt = 0; nt < 4; ++nt)
                        o_acc[qh][nt] = __builtin_amdgcn_mfma_f32_16x16x32_bf16(
                            pf[kk], vf[nt][kk], o_acc[qh][nt], 0, 0, 0);
                }
            }
        }

        // epilogue (o_acc: row=query quad*4+rg, col=dh nt*16+l16)
#pragma unroll
        for (int qh = 0; qh < 2; ++qh) {
            float inv[4];
#pragma unroll
            for (int rg = 0; rg < 4; ++rg) inv[rg] = 1.f / l_acc[qh][rg];
#pragma unroll
            for (int nt = 0; nt < 4; ++nt)
#pragma unroll
                for (int rg = 0; rg < 4; ++rg) {
                    int m = w*32 + qh*16 + quad*4 + rg;
                    OA[((size_t)b*NS + s0 + m)*ND + h*NDH + nt*16 + l16] =
                        f2bf(o_acc[qh][nt][rg] * inv[rg]);
                }
        }
    } else {
        // ---------------- sparse path (fp32 scalar, bf16 inputs) ----------
        const int r2  = lane & 15;
        const int cg  = lane >> 4;
#pragma unroll
        for (int qh = 0; qh < 2; ++qh) {
            const int row = w*32 + qh*16 + r2;

            float qreg[64];
            {
                const ushort* qp = Qh + (size_t)(s0 + row) * NDH;
#pragma unroll
                for (int c = 0; c < 8; ++c) {
                    union { bf16x8 v; ushort s[8]; } qv;
                    qv.v = *(const bf16x8*)(qp + c*8);
#pragma unroll
                    for (int j = 0; j < 8; ++j) qreg[c*8 + j] = bf2f(qv.s[j]);
                }
            }

            float sc[8];
#pragma unroll
            for (int jj = 0; jj < 8; ++jj) {
                int j  = cg*8 + jj;
                int mv = pimask[(size_t)(s0+row)*NKSP + j];
                if (mv) {
                    int kv = pidx[(size_t)(s0+row)*NKSP + j];
                    const ushort* krow = &Kh[(size_t)kv * NDH];
                    float acc = 0.f;
#pragma unroll
                    for (int c = 0; c < 8; ++c) {
                        union { bf16x8 v; ushort s[8]; } kk;
                        kk.v = *(const bf16x8*)(krow + c*8);
#pragma unroll
                        for (int jb = 0; jb < 8; ++jb)
                            acc = fmaf(qreg[c*8 + jb], bf2f(kk.s[jb]), acc);
                    }
                    sc[jj] = acc * SCALE;
                } else {
                    sc[jj] = -INFINITY;
                }
            }
            float mt = sc[0];
#pragma unroll
            for (int jj = 1; jj < 8; ++jj) mt = fmaxf(mt, sc[jj]);
            mt = fmaxf(mt, __shfl_xor(mt, 16));
            mt = fmaxf(mt, __shfl_xor(mt, 32));

            float psum = 0.f;
#pragma unroll
            for (int jj = 0; jj < 8; ++jj) {
                float p = __expf(sc[jj] - mt);
                psum += p;
                Ps[row * 72 + cg*8 + jj] = f2bf(p);
            }
            psum += __shfl_xor(psum, 16);
            psum += __shfl_xor(psum, 32);

            float o[16];
#pragma unroll
            for (int i = 0; i < 16; ++i) o[i] = 0.f;

            for (int j = 0; j < 32; ++j) {
                float p = bf2f(Ps[row * 72 + j]);
                if (p != 0.f) {
                    int kv = pidx[(size_t)(s0+row)*NKSP + j];
                    const ushort* vrow = &Vh[(size_t)kv * NDH + cg*16];
#pragma unroll
                    for (int c = 0; c < 2; ++c) {
                        union { bf16x8 v; ushort s[8]; } vv;
                        vv.v = *(const bf16x8*)(vrow + c*8);
#pragma unroll
                        for (int jb = 0; jb < 8; ++jb)
                            o[c*8 + jb] = fmaf(p, bf2f(vv.s[jb]), o[c*8 + jb]);
                    }
                }
            }

            float inv = 1.f / psum;
            ushort* op = OA + ((size_t)b*NS + s0 + row)*ND + h*NDH + cg*16;
#pragma unroll
            for (int i4 = 0; i4 < 4; ++i4) {
                ushort4 v;
                v.x = f2bf(o[i4*4+0]*inv); v.y = f2bf(o[i4*4+1]*inv);
                v.z = f2bf(o[i4*4+2]*inv); v.w = f2bf(o[i4*4+3]*inv);
                *(ushort4*)(op + i4*4) = v;
            }
        }
    }
}

// ---------------------------------------------------------------------------
extern "C" void kernel_launch(void* const* d_in, const int* in_sizes, int n_in,
                              void* d_out, int out_size, void* d_ws, size_t ws_size,
                              hipStream_t stream)
{
    const float* x      = (const float*)d_in[0];
    const int*   pmask  = (const int*)  d_in[1];
    const int*   pidx   = (const int*)  d_in[2];
    const int*   pimask = (const int*)  d_in[3];
    const float* u_prev = (const float*)d_in[4];
    const float* Wq     = (const float*)d_in[5];
    const float* bq     = (const float*)d_in[6];
    const float* Wk     = (const float*)d_in[7];
    const float* bk     = (const float*)d_in[8];
    const float* Wv     = (const float*)d_in[9];
    const float* bv     = (const float*)d_in[10];
    const float* Wo     = (const float*)d_in[11];
    const float* bo     = (const float*)d_in[12];
    float* out = (float*)d_out;

    const size_t QSZ = (size_t)NB * NH * NS * NDH;   // 4,194,304 elements
    const size_t WSZ = (size_t)ND * ND;              // 1,048,576 elements
    ushort* xb  = (ushort*)d_ws;        // bf16 x              (8 MB)
    ushort* Qw  = xb  + QSZ;            // bf16 Q (b,h,s,dh)   (8 MB)
    ushort* Kw  = Qw  + QSZ;            // bf16 K              (8 MB)
    ushort* Vw  = Kw  + QSZ;            // bf16 V              (8 MB)
    ushort* Vtw = Vw  + QSZ;            // bf16 V^T (b,h,dh,s) (8 MB)
    ushort* Awb = Vtw + QSZ;            // bf16 attn out       (8 MB)
    ushort* Wqb = Awb + QSZ;            // bf16 weights (2 MB each)
    ushort* Wkb = Wqb + WSZ;
    ushort* Wvb = Wkb + WSZ;
    ushort* Wob = Wvb + WSZ;
    u64*    bmw = (u64*)(Wob + WSZ);    // packed mask (128 KB)

    f2bf_multi<<<dim3(4096, 6), 256, 0, stream>>>(
        x, Wq, Wk, Wv, Wo, pmask, xb, Wqb, Wkb, Wvb, Wob, bmw);

    gemm_qkv<<<dim3(24, 32), 256, 0, stream>>>(
        xb, Wqb, Wkb, Wvb, bq, bk, bv, Qw, Kw, Vw, Vtw);

    attn_kernel<<<512, 256, 0, stream>>>(
        Qw, Kw, Vw, Vtw, bmw, pidx, pimask, u_prev, Awb);

    gemm_out<<<dim3(ND/128, (NB*NS)/64), 256, 0, stream>>>(Awb, Wob, bo, out);
}